// Round 3
// baseline (5766.464 us; speedup 1.0000x reference)
//
#include <hip/hip_runtime.h>
#include <math.h>

#define HH 512
#define BB 64
#define SS 48
#define EE 512
#define G4 2048
#define SC 24          // layer-0 scan chunk length (2 chunks of 24 steps)
#define EPSF 1e-5f

// ---- block-wide reduce of float4 over 512 threads (8 waves) ----
__device__ inline float4 blockReduce4(float4 v, float4* red) {
  #pragma unroll
  for (int off = 32; off > 0; off >>= 1) {
    v.x += __shfl_down(v.x, off);
    v.y += __shfl_down(v.y, off);
    v.z += __shfl_down(v.z, off);
    v.w += __shfl_down(v.w, off);
  }
  int lane = threadIdx.x & 63;
  int wid  = threadIdx.x >> 6;
  if (lane == 0) red[wid] = v;
  __syncthreads();
  float4 r = red[0];
  #pragma unroll
  for (int i = 1; i < 8; ++i) {
    float4 t = red[i];
    r.x += t.x; r.y += t.y; r.z += t.z; r.w += t.w;
  }
  __syncthreads();
  return r;
}

// ---- 256-thread sum+sumsq (for ln_rows) ----
__device__ inline float2 blockReduceSumSq256(float s, float q, float* red) {
  #pragma unroll
  for (int off = 32; off > 0; off >>= 1) {
    s += __shfl_down(s, off);
    q += __shfl_down(q, off);
  }
  int lane = threadIdx.x & 63;
  int wid  = threadIdx.x >> 6;
  if (lane == 0) { red[wid] = s; red[4 + wid] = q; }
  __syncthreads();
  float ts = red[0] + red[1] + red[2] + red[3];
  float tq = red[4] + red[5] + red[6] + red[7];
  __syncthreads();
  return make_float2(ts, tq);
}

// ---- plain GEMM C[m,n] = sum_k A[m*K+k]*W[n*K+k]; 64x64 tile ----
__global__ __launch_bounds__(256)
void gemm_nt64(const float* __restrict__ A, const float* __restrict__ Wm,
               float* __restrict__ C, int N, int K) {
  __shared__ float As[16][65];
  __shared__ float Bs[16][65];
  const int bm = blockIdx.y * 64;
  const int bn = blockIdx.x * 64;
  const int tid = threadIdx.x;
  const int lrow = tid >> 2;
  const int lkk  = (tid & 3) << 2;
  const int tx = tid & 15;
  const int ty = tid >> 4;
  float acc[4][4] = {};
  for (int k0 = 0; k0 < K; k0 += 16) {
    float4 av = *(const float4*)(A  + (size_t)(bm + lrow) * K + k0 + lkk);
    float4 bv = *(const float4*)(Wm + (size_t)(bn + lrow) * K + k0 + lkk);
    As[lkk+0][lrow] = av.x; As[lkk+1][lrow] = av.y; As[lkk+2][lrow] = av.z; As[lkk+3][lrow] = av.w;
    Bs[lkk+0][lrow] = bv.x; Bs[lkk+1][lrow] = bv.y; Bs[lkk+2][lrow] = bv.z; Bs[lkk+3][lrow] = bv.w;
    __syncthreads();
    #pragma unroll
    for (int k = 0; k < 16; ++k) {
      float a[4], b[4];
      #pragma unroll
      for (int i = 0; i < 4; ++i) a[i] = As[k][ty*4+i];
      #pragma unroll
      for (int j = 0; j < 4; ++j) b[j] = Bs[k][tx*4+j];
      #pragma unroll
      for (int i = 0; i < 4; ++i)
        #pragma unroll
        for (int j = 0; j < 4; ++j) acc[i][j] += a[i]*b[j];
    }
    __syncthreads();
  }
  for (int i = 0; i < 4; ++i)
    for (int j = 0; j < 4; ++j)
      C[(size_t)(bm + ty*4 + i) * N + bn + tx*4 + j] = acc[i][j];
}

// ---- layer-0 input projection for one time-chunk, both directions ----
// Gc rows m = d*(B*SC) + b*SC + tl ; maps to x row b*SS + s,
// s = (d==0 ? t0+tl : SS-1-t0-tl). N=G4, K=EE.
__global__ __launch_bounds__(256)
void gemm_ih0(const float* __restrict__ x, const float* __restrict__ w_ih0,
              float* __restrict__ Gc, int t0) {
  __shared__ float As[16][65];
  __shared__ float Bs[16][65];
  const int m0 = blockIdx.y * 64;
  const int d  = m0 / (BB * SC);          // uniform per block (BB*SC % 64 == 0)
  const float* Wm = w_ih0 + (size_t)d * G4 * EE;
  const int bn = blockIdx.x * 64;
  const int tid = threadIdx.x;
  const int lrow = tid >> 2;
  const int lkk  = (tid & 3) << 2;
  const int tx = tid & 15;
  const int ty = tid >> 4;
  // A row remap for this thread's load row
  int m  = m0 + lrow;
  int r  = m - d * (BB * SC);
  int b  = r / SC;
  int tl = r - b * SC;
  int s  = d ? (SS - 1 - t0 - tl) : (t0 + tl);
  const float* arow = x + ((size_t)b * SS + s) * EE;

  float acc[4][4] = {};
  for (int k0 = 0; k0 < EE; k0 += 16) {
    float4 av = *(const float4*)(arow + k0 + lkk);
    float4 bv = *(const float4*)(Wm + (size_t)(bn + lrow) * EE + k0 + lkk);
    As[lkk+0][lrow] = av.x; As[lkk+1][lrow] = av.y; As[lkk+2][lrow] = av.z; As[lkk+3][lrow] = av.w;
    Bs[lkk+0][lrow] = bv.x; Bs[lkk+1][lrow] = bv.y; Bs[lkk+2][lrow] = bv.z; Bs[lkk+3][lrow] = bv.w;
    __syncthreads();
    #pragma unroll
    for (int k = 0; k < 16; ++k) {
      float a[4], bbv[4];
      #pragma unroll
      for (int i = 0; i < 4; ++i) a[i] = As[k][ty*4+i];
      #pragma unroll
      for (int j = 0; j < 4; ++j) bbv[j] = Bs[k][tx*4+j];
      #pragma unroll
      for (int i = 0; i < 4; ++i)
        #pragma unroll
        for (int j = 0; j < 4; ++j) acc[i][j] += a[i]*bbv[j];
    }
    __syncthreads();
  }
  for (int i = 0; i < 4; ++i)
    for (int j = 0; j < 4; ++j)
      Gc[(size_t)(m0 + ty*4 + i) * G4 + bn + tx*4 + j] = acc[i][j];
}

// ---- in-place LayerNorm on rows of 2048 ----
__global__ __launch_bounds__(256)
void ln_rows(float* __restrict__ X, const float* __restrict__ gamma,
             const float* __restrict__ beta, int rows_per_d) {
  __shared__ float red[8];
  const int row = blockIdx.x;
  const int d = row / rows_per_d;
  float* xr = X + (size_t)row * G4;
  const float* gg = gamma + (size_t)d * G4;
  const float* bb = beta  + (size_t)d * G4;
  float s = 0.f, q = 0.f;
  float v[8];
  #pragma unroll
  for (int it = 0; it < 8; ++it) {
    float xv = xr[threadIdx.x + it*256];
    v[it] = xv; s += xv; q += xv*xv;
  }
  float2 t = blockReduceSumSq256(s, q, red);
  float mu = t.x * (1.f/G4);
  float var = t.y * (1.f/G4) - mu*mu;
  float rstd = rsqrtf(var + EPSF);
  #pragma unroll
  for (int it = 0; it < 8; ++it) {
    int jc = threadIdx.x + it*256;
    xr[jc] = (v[it]-mu)*rstd*gg[jc] + bb[jc];
  }
}

// ---- W_hh [2][2048][512] fp32 -> Wt [d][512][2048] fp32 (transposed) ----
__global__ __launch_bounds__(256)
void transpose_f32(const float* __restrict__ src0, float* __restrict__ dst) {
  __shared__ float tile[64][65];
  const int dd = blockIdx.z;
  const float* src = src0 + (size_t)dd * G4 * HH;
  float* dst_d = dst + (size_t)dd * HH * G4;
  const int bn = blockIdx.x * 64;   // n (rows of src)
  const int bk = blockIdx.y * 64;   // k (cols of src)
  const int tx = threadIdx.x & 63;
  const int ty = threadIdx.x >> 6;
  #pragma unroll
  for (int jj = 0; jj < 16; ++jj) {
    int r = ty * 16 + jj;
    tile[r][tx] = src[(size_t)(bn + r) * HH + bk + tx];
  }
  __syncthreads();
  #pragma unroll
  for (int jj = 0; jj < 16; ++jj) {
    int r = ty * 16 + jj;   // local k
    dst_d[(size_t)(bk + r) * G4 + bn + tx] = tile[tx][r];
  }
}

// ---- fused scan: one block per (d, batch-pair), nsteps, fp32 throughout ----
// Wt: [d][512][2048] fp32. G time index t (already chunk/direction-resolved).
__global__ __launch_bounds__(512)
void lstm_scan2(const float* __restrict__ Wt, const float* __restrict__ G,
                long g_db_stride, long g_t_stride,
                const float* __restrict__ lnhg, const float* __restrict__ lnhb,
                const float* __restrict__ lnog, const float* __restrict__ lnob,
                float* __restrict__ hio, float* __restrict__ cio,
                float* __restrict__ outp, int nsteps) {
  __shared__ float hs0[HH], hs1[HH];
  __shared__ float Rs0[G4], Rs1[G4];
  __shared__ float4 red4[8];
  const int tid = threadIdx.x;
  const int d  = blockIdx.x & 1;      // parity -> XCD locality for weight slab
  const int bp = blockIdx.x >> 1;
  const int b0 = bp * 2, b1 = b0 + 1;
  const int db0 = d * BB + b0, db1 = db0 + 1;
  const float* Wd = Wt + (size_t)d * HH * G4 + 4 * tid;
  const float* gb0 = G + (size_t)db0 * g_db_stride;
  const float* gb1 = G + (size_t)db1 * g_db_stride;
  const float* hg = lnhg + (size_t)d * G4;
  const float* hb = lnhb + (size_t)d * G4;
  const float* og = lnog + (size_t)d * HH;
  const float* ob = lnob + (size_t)d * HH;

  hs0[tid] = hio[(size_t)db0 * HH + tid];
  hs1[tid] = hio[(size_t)db1 * HH + tid];
  float c0 = cio[(size_t)db0 * HH + tid];
  float c1 = cio[(size_t)db1 * HH + tid];
  __syncthreads();

  for (int t = 0; t < nsteps; ++t) {
    // ---- GEMV: thread owns 4 n-cols for 2 batches ----
    float4 A0 = {0.f,0.f,0.f,0.f}, A1 = {0.f,0.f,0.f,0.f};
    #pragma unroll 4
    for (int k = 0; k < HH; k += 4) {
      float4 h0 = *(const float4*)(hs0 + k);
      float4 h1 = *(const float4*)(hs1 + k);
      const float* wp = Wd + (size_t)k * G4;
      float4 w0 = *(const float4*)(wp);
      float4 w1 = *(const float4*)(wp + G4);
      float4 w2 = *(const float4*)(wp + 2*G4);
      float4 w3 = *(const float4*)(wp + 3*G4);
      A0.x += h0.x*w0.x + h0.y*w1.x + h0.z*w2.x + h0.w*w3.x;
      A0.y += h0.x*w0.y + h0.y*w1.y + h0.z*w2.y + h0.w*w3.y;
      A0.z += h0.x*w0.z + h0.y*w1.z + h0.z*w2.z + h0.w*w3.z;
      A0.w += h0.x*w0.w + h0.y*w1.w + h0.z*w2.w + h0.w*w3.w;
      A1.x += h1.x*w0.x + h1.y*w1.x + h1.z*w2.x + h1.w*w3.x;
      A1.y += h1.x*w0.y + h1.y*w1.y + h1.z*w2.y + h1.w*w3.y;
      A1.z += h1.x*w0.z + h1.y*w1.z + h1.z*w2.z + h1.w*w3.z;
      A1.w += h1.x*w0.w + h1.y*w1.w + h1.z*w2.w + h1.w*w3.w;
    }
    Rs0[4*tid+0] = A0.x; Rs0[4*tid+1] = A0.y; Rs0[4*tid+2] = A0.z; Rs0[4*tid+3] = A0.w;
    Rs1[4*tid+0] = A1.x; Rs1[4*tid+1] = A1.y; Rs1[4*tid+2] = A1.z; Rs1[4*tid+3] = A1.w;
    float4 sq;
    sq.x = A0.x + A0.y + A0.z + A0.w;
    sq.y = A0.x*A0.x + A0.y*A0.y + A0.z*A0.z + A0.w*A0.w;
    sq.z = A1.x + A1.y + A1.z + A1.w;
    sq.w = A1.x*A1.x + A1.y*A1.y + A1.z*A1.z + A1.w*A1.w;
    float4 rr = blockReduce4(sq, red4);   // syncs; also fences Rs writes
    float mu0 = rr.x * (1.f/G4), rstd0 = rsqrtf(rr.y*(1.f/G4) - mu0*mu0 + EPSF);
    float mu1 = rr.z * (1.f/G4), rstd1 = rsqrtf(rr.w*(1.f/G4) - mu1*mu1 + EPSF);

    // ---- gates + cell update; thread owns column n = tid ----
    const float* gr0 = gb0 + (size_t)t * g_t_stride;
    const float* gr1 = gb1 + (size_t)t * g_t_stride;
    const int n = tid;
    float gi0 = gr0[n]        + (Rs0[n]        - mu0)*rstd0*hg[n]        + hb[n];
    float gf0 = gr0[HH+n]     + (Rs0[HH+n]     - mu0)*rstd0*hg[HH+n]     + hb[HH+n];
    float go0 = gr0[2*HH+n]   + (Rs0[2*HH+n]   - mu0)*rstd0*hg[2*HH+n]   + hb[2*HH+n];
    float gt0 = gr0[3*HH+n]   + (Rs0[3*HH+n]   - mu0)*rstd0*hg[3*HH+n]   + hb[3*HH+n];
    float gi1 = gr1[n]        + (Rs1[n]        - mu1)*rstd1*hg[n]        + hb[n];
    float gf1 = gr1[HH+n]     + (Rs1[HH+n]     - mu1)*rstd1*hg[HH+n]     + hb[HH+n];
    float go1 = gr1[2*HH+n]   + (Rs1[2*HH+n]   - mu1)*rstd1*hg[2*HH+n]   + hb[2*HH+n];
    float gt1 = gr1[3*HH+n]   + (Rs1[3*HH+n]   - mu1)*rstd1*hg[3*HH+n]   + hb[3*HH+n];
    float iv0 = 1.f/(1.f+expf(-gi0)), fv0 = 1.f/(1.f+expf(-gf0));
    float ov0 = 1.f/(1.f+expf(-go0)), gv0 = tanhf(gt0);
    float iv1 = 1.f/(1.f+expf(-gi1)), fv1 = 1.f/(1.f+expf(-gf1));
    float ov1 = 1.f/(1.f+expf(-go1)), gv1 = tanhf(gt1);
    c0 = fv0*c0 + iv0*gv0;
    c1 = fv1*c1 + iv1*gv1;

    float4 cq; cq.x = c0; cq.y = c0*c0; cq.z = c1; cq.w = c1*c1;
    float4 cr = blockReduce4(cq, red4);
    float muc0 = cr.x*(1.f/HH), rsc0 = rsqrtf(cr.y*(1.f/HH) - muc0*muc0 + EPSF);
    float muc1 = cr.z*(1.f/HH), rsc1 = rsqrtf(cr.w*(1.f/HH) - muc1*muc1 + EPSF);
    hs0[n] = ov0 * tanhf((c0 - muc0)*rsc0*og[n] + ob[n]);
    hs1[n] = ov1 * tanhf((c1 - muc1)*rsc1*og[n] + ob[n]);
    __syncthreads();
  }
  hio[(size_t)db0 * HH + tid] = hs0[tid];
  hio[(size_t)db1 * HH + tid] = hs1[tid];
  cio[(size_t)db0 * HH + tid] = c0;
  cio[(size_t)db1 * HH + tid] = c1;
  outp[(size_t)b0 * (2*HH) + (size_t)d * HH + tid] = hs0[tid];
  outp[(size_t)b1 * (2*HH) + (size_t)d * HH + tid] = hs1[tid];
}

extern "C" void kernel_launch(void* const* d_in, const int* in_sizes, int n_in,
                              void* d_out, int out_size, void* d_ws, size_t ws_size,
                              hipStream_t stream) {
  const float* x        = (const float*)d_in[0];
  const float* w_ih0    = (const float*)d_in[2];
  const float* w_hh0    = (const float*)d_in[3];
  const float* ln_ih0_g = (const float*)d_in[4];
  const float* ln_ih0_b = (const float*)d_in[5];
  const float* ln_hh0_g = (const float*)d_in[6];
  const float* ln_hh0_b = (const float*)d_in[7];
  const float* ln_ho0_g = (const float*)d_in[8];
  const float* ln_ho0_b = (const float*)d_in[9];
  const float* w_ih1    = (const float*)d_in[10];
  const float* w_hh1    = (const float*)d_in[11];
  const float* ln_ih1_g = (const float*)d_in[12];
  const float* ln_ih1_b = (const float*)d_in[13];
  const float* ln_hh1_g = (const float*)d_in[14];
  const float* ln_hh1_b = (const float*)d_in[15];
  const float* ln_ho1_g = (const float*)d_in[16];
  const float* ln_ho1_b = (const float*)d_in[17];
  float* out = (float*)d_out;

  // ws layout (floats): Wt 2.10M | Gc 6.29M | g1pre 0.26M | hio 64K | cio 64K  ~= 35 MB
  float* ws    = (float*)d_ws;
  float* Wt    = ws;                             // [2][512][2048] fp32, per-layer reuse
  float* Gc    = Wt + (size_t)2*HH*G4;           // [2][B][SC][2048]
  float* g1pre = Gc + (size_t)2*BB*SC*G4;        // [2][B][2048]
  float* hio   = g1pre + (size_t)2*BB*G4;        // [2][B][512]
  float* cio   = hio + (size_t)2*BB*HH;          // [2][B][512]

  // ---- layer 0 ----
  hipLaunchKernelGGL(transpose_f32, dim3(G4/64, HH/64, 2), dim3(256), 0, stream, w_hh0, Wt);
  hipMemsetAsync(hio, 0, (size_t)4*BB*HH*sizeof(float), stream);   // hio+cio contiguous

  for (int ch = 0; ch < SS/SC; ++ch) {
    hipLaunchKernelGGL(gemm_ih0, dim3(G4/64, (2*BB*SC)/64), dim3(256), 0, stream,
        x, w_ih0, Gc, ch*SC);
    hipLaunchKernelGGL(ln_rows, dim3(2*BB*SC), dim3(256), 0, stream,
        Gc, ln_ih0_g, ln_ih0_b, BB*SC);
    hipLaunchKernelGGL(lstm_scan2, dim3(BB), dim3(512), 0, stream,
        Wt, Gc, (long)SC*G4, (long)G4,
        ln_hh0_g, ln_hh0_b, ln_ho0_g, ln_ho0_b, hio, cio, out /*xc scratch*/, SC);
  }

  // ---- layer 1 input projection (xc currently lives in d_out) ----
  for (int d = 0; d < 2; ++d)
    hipLaunchKernelGGL(gemm_nt64, dim3(G4/64, 1), dim3(256), 0, stream,
        out, w_ih1 + (size_t)d*G4*(2*HH), g1pre + (size_t)d*BB*G4, G4, 2*HH);
  hipLaunchKernelGGL(ln_rows, dim3(2*BB), dim3(256), 0, stream,
      g1pre, ln_ih1_g, ln_ih1_b, BB);

  // ---- layer 1 ----
  hipLaunchKernelGGL(transpose_f32, dim3(G4/64, HH/64, 2), dim3(256), 0, stream, w_hh1, Wt);
  hipMemsetAsync(hio, 0, (size_t)4*BB*HH*sizeof(float), stream);
  hipLaunchKernelGGL(lstm_scan2, dim3(BB), dim3(512), 0, stream,
      Wt, g1pre, (long)G4, 0L,
      ln_hh1_g, ln_hh1_b, ln_ho1_g, ln_ho1_b, hio, cio, out, SS);
}